// Round 5
// baseline (811.063 us; speedup 1.0000x reference)
//
#include <hip/hip_runtime.h>
#include <hip/hip_bf16.h>

// MHA: y = softmax(mask(QK^T/8)) V, with bf16 MFMA pipeline.
// B=4, S=2048, D=1024, H=16, Dh=64.
// Q-projection prescaled by 0.125*log2(e): softmax computed in base-2 domain.
// Softmax denominator computed by MFMA (ones-row x P^T), not VALU.

typedef __attribute__((ext_vector_type(8))) short bf16x8;
typedef __attribute__((ext_vector_type(4))) float f32x4;
typedef unsigned int u32;
typedef unsigned short u16;
typedef unsigned long long u64;

#define SEQ 2048
#define DM 1024
#define NH 16
#define HD 64

// ---------- helpers ----------
__device__ __forceinline__ u16 f2bf(float f) {
  // compiler pairs adjacent casts into v_cvt_pk_bf16_f32 (m240)
  __hip_bfloat16 h = __float2bfloat16(f);
  return __builtin_bit_cast(u16, h);
}
__device__ __forceinline__ u32 pack2(float a, float b) {
  return (u32)f2bf(a) | ((u32)f2bf(b) << 16);
}
__device__ __forceinline__ float max3f(float a, float b, float c) {
  return fmaxf(fmaxf(a, b), c);   // fuses to v_max3_f32
}

typedef __attribute__((address_space(3))) u32 lds_u32;
typedef const __attribute__((address_space(1))) u32 gbl_u32;
__device__ __forceinline__ void gll16(const void* g, void* l) {
  // async global->LDS, 16B per lane; dest must be linear (wave base + lane*16)
  __builtin_amdgcn_global_load_lds((gbl_u32*)g, (lds_u32*)l, 16, 0, 0);
}

// ---------- fp32 -> bf16 cast of inputs+weights (segments contiguous in ws) ----------
__global__ __launch_bounds__(256) void cast_all(
    const float* __restrict__ q, const float* __restrict__ k, const float* __restrict__ v,
    const float* __restrict__ wq, const float* __restrict__ wk,
    const float* __restrict__ wv, const float* __restrict__ wf,
    u16* __restrict__ dst)
{
  int i4 = blockIdx.x * 256 + threadIdx.x;   // one float4 per thread, grid exact
  const float* s; int rel;
  if      (i4 < 2097152) { s = q;  rel = i4;           }
  else if (i4 < 4194304) { s = k;  rel = i4 - 2097152; }
  else if (i4 < 6291456) { s = v;  rel = i4 - 4194304; }
  else if (i4 < 6553600) { s = wq; rel = i4 - 6291456; }
  else if (i4 < 6815744) { s = wk; rel = i4 - 6553600; }
  else if (i4 < 7077888) { s = wv; rel = i4 - 6815744; }
  else                   { s = wf; rel = i4 - 7077888; }
  float4 val = ((const float4*)s)[rel];
  uint2 o; o.x = pack2(val.x, val.y); o.y = pack2(val.z, val.w);
  ((uint2*)dst)[i4] = o;
}

// ---------- int32 mask -> bitmask (1 bit per entry) ----------
__global__ __launch_bounds__(256) void maskbits(const int* __restrict__ mask, u32* __restrict__ bm) {
  int t = blockIdx.x * 256 + threadIdx.x;
  int v = mask[t];
  u64 bal = __ballot(v != 0);
  if ((threadIdx.x & 63) == 0) {
    bm[(t >> 5)]     = (u32)bal;
    bm[(t >> 5) + 1] = (u32)(bal >> 32);
  }
}

// ---------- GEMM: D[mi][ni] = sum_k Pm[mi][k]*Pn[ni][k]  (K=1024, bf16, fp32 acc) ----------
// MODE 0: Pm=W(1024r) Pn=X(8192r), out bf16 [B,H,S,64], bias[mi]     (Q,K proj)
// MODE 1: Pm=X(8192r) Pn=W(1024r), out bf16 [B,H,64,S] (V^T), bias[ni]
// MODE 2: Pm=W(1024r) Pn=AO(8192r), out fp32 [8192,1024], bias[mi]   (FC)
// scale: applied to (acc+bias) before store (Q-proj: 0.125*log2e; else 1.0)
template<int MODE>
__global__ __launch_bounds__(256) void gemm_bt(
    const u16* __restrict__ Pm, const u16* __restrict__ Pn,
    const float* __restrict__ bias, void* __restrict__ outp, float scale)
{
  __shared__ alignas(16) u16 Al[128 * 32];
  __shared__ alignas(16) u16 Bl[128 * 32];
  const int tid = threadIdx.x;
  const int l = tid & 63;
  const int wv = tid >> 6;
  const int lane15 = l & 15, g = l >> 4;
  const int wr = wv >> 1, wc = wv & 1;
  const int mBase = blockIdx.y * 128, nBase = blockIdx.x * 128;

  f32x4 acc[4][4];
#pragma unroll
  for (int a = 0; a < 4; ++a)
#pragma unroll
    for (int b = 0; b < 4; ++b) acc[a][b] = (f32x4){0.f, 0.f, 0.f, 0.f};

  const int srow = tid >> 2, skc = tid & 3;       // staging: row, 8-elem k-chunk
  const u16* gA = Pm + (size_t)(mBase + srow) * 1024 + skc * 8;
  const u16* gB = Pn + (size_t)(nBase + srow) * 1024 + skc * 8;

  for (int kt = 0; kt < 32; ++kt) {
    __syncthreads();
    const u16* a0 = gA + kt * 32;
    const u16* b0 = gB + kt * 32;
    gll16(a0,             &Al[tid * 8]);
    gll16(a0 + 64 * 1024, &Al[(tid + 256) * 8]);
    gll16(b0,             &Bl[tid * 8]);
    gll16(b0 + 64 * 1024, &Bl[(tid + 256) * 8]);
    __syncthreads();
    bf16x8 af[4], bff[4];
#pragma unroll
    for (int mt = 0; mt < 4; ++mt)
      af[mt] = *(const bf16x8*)&Al[(wr * 64 + mt * 16 + lane15) * 32 + g * 8];
#pragma unroll
    for (int nt = 0; nt < 4; ++nt)
      bff[nt] = *(const bf16x8*)&Bl[(wc * 64 + nt * 16 + lane15) * 32 + g * 8];
#pragma unroll
    for (int mt = 0; mt < 4; ++mt)
#pragma unroll
      for (int nt = 0; nt < 4; ++nt)
        acc[mt][nt] = __builtin_amdgcn_mfma_f32_16x16x32_bf16(af[mt], bff[nt], acc[mt][nt], 0, 0, 0);
  }

#pragma unroll
  for (int mt = 0; mt < 4; ++mt) {
    const int mi = mBase + wr * 64 + mt * 16 + g * 4;   // +reg (0..3) consecutive
#pragma unroll
    for (int nt = 0; nt < 4; ++nt) {
      const int ni = nBase + wc * 64 + nt * 16 + lane15;
      f32x4 v = acc[mt][nt];
      if constexpr (MODE == 0) {
        f32x4 bb = *(const f32x4*)&bias[mi];
        int b = ni >> 11, s = ni & 2047;
        int h = mi >> 6, dh = mi & 63;
        uint2 w;
        w.x = pack2((v[0] + bb[0]) * scale, (v[1] + bb[1]) * scale);
        w.y = pack2((v[2] + bb[2]) * scale, (v[3] + bb[3]) * scale);
        *(uint2*)&((u16*)outp)[((size_t)((b << 4) + h) * SEQ + s) * HD + dh] = w;
      } else if constexpr (MODE == 1) {
        float bv = bias[ni];
        int b = mi >> 11, s = mi & 2047;
        int h = ni >> 6, dh = ni & 63;
        uint2 w;
        w.x = pack2(v[0] + bv, v[1] + bv);
        w.y = pack2(v[2] + bv, v[3] + bv);
        *(uint2*)&((u16*)outp)[((size_t)((b << 4) + h) * HD + dh) * SEQ + s] = w;
      } else {
        f32x4 bb = *(const f32x4*)&bias[mi];
        f32x4 w = v + bb;
        *(f32x4*)&((float*)outp)[(size_t)ni * 1024 + mi] = w;
      }
    }
  }
}

// ---------- flash attention, 4 waves x 16 q-rows, KBLK=64, swapped-operand MFMA ----------
// Scores arrive in log2 domain (Q prescaled); softmax via exp2.
// Denominator: accSum = ones x P^T via MFMA (each lane's col q16 holds its row-sum).
__global__ __launch_bounds__(256) void attn_kernel(
    const u16* __restrict__ Qb, const u16* __restrict__ Kb,
    const u16* __restrict__ Vt, const u32* __restrict__ bm,
    u16* __restrict__ AO)
{
  __shared__ uint2 Pl[4][256];   // per-wave 2KB: P^T tile [16 q][64 k] bf16, XOR-swizzled 8B units
  const int bid = blockIdx.x;
  const int bh = (bid & 7) * 8 + ((bid >> 3) & 7);   // all q-tiles of a head share an XCD
  const int qt = bid >> 6;
  const int b = bh >> 4, h = bh & 15;
  const int tid = threadIdx.x;
  const int wv = tid >> 6, l = tid & 63;
  const int q16 = l & 15, g = l >> 4;

  const u16* Qp = Qb + (size_t)bh * SEQ * HD;
  const u16* Kp = Kb + (size_t)bh * SEQ * HD;
  const u16* Vp = Vt + (size_t)bh * HD * SEQ;
  const int qrow = qt * 64 + wv * 16;

  const bf16x8 qf0 = *(const bf16x8*)&Qp[(qrow + q16) * HD + g * 8];
  const bf16x8 qf1 = *(const bf16x8*)&Qp[(qrow + q16) * HD + 32 + g * 8];
  const u32* bmq = bm + (size_t)(b * SEQ + qrow + q16) * (SEQ / 32);

  // all-ones bf16 A-fragment for the denominator MFMA
  union { u32 u[4]; bf16x8 v; } ones;
  ones.u[0] = ones.u[1] = ones.u[2] = ones.u[3] = 0x3F803F80u;

  // Defer-max base: scores (log2 domain) have |s| << 8 for normalized inputs;
  // rescale branch below keeps correctness for arbitrary inputs (fires if pmax>mrun+12).
  float mrun = 8.0f;
  f32x4 accO[4], accSum;
#pragma unroll
  for (int dt = 0; dt < 4; ++dt) accO[dt] = (f32x4){0.f, 0.f, 0.f, 0.f};
  accSum = (f32x4){0.f, 0.f, 0.f, 0.f};
  const f32x4 z = {0.f, 0.f, 0.f, 0.f};

  for (int kb = 0; kb < SEQ / 64; ++kb) {
    const int k0 = kb * 64;
    f32x4 accS[4];
    __builtin_amdgcn_s_setprio(1);
#pragma unroll
    for (int n = 0; n < 4; ++n) {    // S^T tile: rows k, cols q
      bf16x8 kf0 = *(const bf16x8*)&Kp[(k0 + n * 16 + q16) * HD + g * 8];
      bf16x8 kf1 = *(const bf16x8*)&Kp[(k0 + n * 16 + q16) * HD + 32 + g * 8];
      accS[n] = __builtin_amdgcn_mfma_f32_16x16x32_bf16(kf0, qf0, z, 0, 0, 0);
      accS[n] = __builtin_amdgcn_mfma_f32_16x16x32_bf16(kf1, qf1, accS[n], 0, 0, 0);
    }
    __builtin_amdgcn_s_setprio(0);
    const u32 w0 = bmq[kb * 2], w1 = bmq[kb * 2 + 1];
    float s[16];
#pragma unroll
    for (int n = 0; n < 4; ++n) {
      const u32 nib = ((n & 2) ? w1 : w0) >> ((n & 1) * 16 + g * 4);  // 4 mask bits for this group
#pragma unroll
      for (int r = 0; r < 4; ++r)
        s[n * 4 + r] = ((nib >> r) & 1u) ? accS[n][r] : -1e9f;
    }
    // max over 16 via v_max3 tree, then across the 4 k-groups
    float pmax;
    {
      float g0 = max3f(s[0],  s[1],  s[2]);
      float g1 = max3f(s[3],  s[4],  s[5]);
      float g2 = max3f(s[6],  s[7],  s[8]);
      float g3 = max3f(s[9],  s[10], s[11]);
      float g4 = max3f(s[12], s[13], s[14]);
      pmax = max3f(max3f(g0, g1, g2), max3f(g3, g4, s[15]), -INFINITY);
    }
    pmax = fmaxf(pmax, __shfl_xor(pmax, 16));
    pmax = fmaxf(pmax, __shfl_xor(pmax, 32));

    // T13 defer-max: rescale only if tile max exceeds running base by >12 (p<=2^12 bounded)
    if (!__all(pmax - mrun <= 12.0f)) {
      const float mnew = fmaxf(mrun, pmax);
      const float alpha = exp2f(mrun - mnew);
      accSum[0] *= alpha;
#pragma unroll
      for (int dt = 0; dt < 4; ++dt) {
        accO[dt][0] *= alpha; accO[dt][1] *= alpha;
        accO[dt][2] *= alpha; accO[dt][3] *= alpha;
      }
      mrun = mnew;
    }

    u16 pb[16];
#pragma unroll
    for (int i = 0; i < 16; ++i)
      pb[i] = f2bf(exp2f(s[i] - mrun));   // bare v_exp_f32 + paired cvt

    // write P^T (bf16) to per-wave LDS, 8B units XOR-swizzled by q
#pragma unroll
    for (int n = 0; n < 4; ++n) {
      uint2 pw;
      pw.x = (u32)pb[n * 4 + 0] | ((u32)pb[n * 4 + 1] << 16);
      pw.y = (u32)pb[n * 4 + 2] | ((u32)pb[n * 4 + 3] << 16);
      Pl[wv][q16 * 16 + ((n * 4 + g) ^ q16)] = pw;
    }
    asm volatile("s_waitcnt lgkmcnt(0)" ::: "memory");
    __builtin_amdgcn_sched_barrier(0);   // rule #18: don't hoist reads/MFMA past the wait
#pragma unroll
    for (int ch = 0; ch < 2; ++ch) {
      const int u0 = ch * 8 + g * 2;
      uint2 lo = Pl[wv][q16 * 16 + ((u0 + 0) ^ q16)];
      uint2 hi = Pl[wv][q16 * 16 + ((u0 + 1) ^ q16)];
      union { u32 u[4]; bf16x8 v; } pf;
      pf.u[0] = lo.x; pf.u[1] = lo.y; pf.u[2] = hi.x; pf.u[3] = hi.y;
      __builtin_amdgcn_s_setprio(1);
#pragma unroll
      for (int dt = 0; dt < 4; ++dt) {
        bf16x8 vf = *(const bf16x8*)&Vp[(dt * 16 + q16) * SEQ + k0 + ch * 32 + g * 8];
        accO[dt] = __builtin_amdgcn_mfma_f32_16x16x32_bf16(vf, pf.v, accO[dt], 0, 0, 0);
      }
      // denominator: D[i][q] = sum_k 1 * P^T[k][q]; every reg of lane's col q16 = row-sum
      accSum = __builtin_amdgcn_mfma_f32_16x16x32_bf16(ones.v, pf.v, accSum, 0, 0, 0);
      __builtin_amdgcn_s_setprio(0);
    }
  }
  const float inv = 1.f / fmaxf(accSum[0], 1e-37f);
#pragma unroll
  for (int dt = 0; dt < 4; ++dt) {
    uint2 o;
    o.x = pack2(accO[dt][0] * inv, accO[dt][1] * inv);
    o.y = pack2(accO[dt][2] * inv, accO[dt][3] * inv);
    *(uint2*)&AO[(size_t)(b * SEQ + qrow + q16) * DM + h * HD + dt * 16 + g * 4] = o;
  }
}

// ---------- launch ----------
extern "C" void kernel_launch(void* const* d_in, const int* in_sizes, int n_in,
                              void* d_out, int out_size, void* d_ws, size_t ws_size,
                              hipStream_t stream) {
  const float* q  = (const float*)d_in[0];
  const float* k  = (const float*)d_in[1];
  const float* v  = (const float*)d_in[2];
  const int* mask = (const int*)d_in[3];
  const float* wq = (const float*)d_in[4];
  const float* bq = (const float*)d_in[5];
  const float* wk = (const float*)d_in[6];
  const float* bk = (const float*)d_in[7];
  const float* wv = (const float*)d_in[8];
  const float* bv = (const float*)d_in[9];
  const float* wf = (const float*)d_in[10];
  const float* bf = (const float*)d_in[11];

  // Workspace layout (u16 units). AO aliases XQ (XQ dead after Q-proj GEMM).
  u16* XQ = (u16*)d_ws;            // 8388608 u16 each for X tensors
  u16* XK = XQ + 8388608;
  u16* XV = XK + 8388608;
  u16* WQ = XV + 8388608;          // 1048576 u16 each for weights
  u16* WK = WQ + 1048576;
  u16* WV = WK + 1048576;
  u16* WF = WV + 1048576;
  u16* QB = WF + 1048576;          // projections, [B,H,S,64] (Q prescaled by 0.125*log2e)
  u16* KB = QB + 8388608;
  u16* VT = KB + 8388608;          // [B,H,64,S]
  u32* BM = (u32*)(VT + 8388608);  // bitmask [B][S][64] words (2 MB)
  u16* AO = XQ;                    // attn out merged [8192,1024] — reuses XQ

  const float qscale = 0.125f * 1.44269504088896f;   // 1/sqrt(Dh) * log2(e)

  cast_all<<<28672, 256, 0, stream>>>(q, k, v, wq, wk, wv, wf, XQ);
  maskbits<<<65536, 256, 0, stream>>>(mask, BM);
  gemm_bt<0><<<dim3(64, 8), 256, 0, stream>>>(WQ, XQ, bq, QB, qscale);
  gemm_bt<0><<<dim3(64, 8), 256, 0, stream>>>(WK, XK, bk, KB, 1.0f);
  gemm_bt<1><<<dim3(8, 64), 256, 0, stream>>>(XV, WV, bv, VT, 1.0f);
  attn_kernel<<<2048, 256, 0, stream>>>(QB, KB, VT, BM, AO);
  gemm_bt<2><<<dim3(64, 8), 256, 0, stream>>>(WF, AO, bf, (float*)d_out, 1.0f);
}

// Round 6
// 487.662 us; speedup vs baseline: 1.6632x; 1.6632x over previous
//
#include <hip/hip_runtime.h>
#include <hip/hip_bf16.h>

// MHA: y = softmax(mask(QK^T/8)) V, with bf16 MFMA pipeline.
// B=4, S=2048, D=1024, H=16, Dh=64.
// Q-projection prescaled by 0.125*log2(e): softmax computed in base-2 domain.
// Softmax denominator computed by MFMA (ones-row x P^T), not VALU.
// R5: attention K/V tiles staged in LDS via global_load_lds (XOR-swizzled source),
//     double-buffered with counted vmcnt + raw s_barrier (fixes TA address-divergence stall).

typedef __attribute__((ext_vector_type(8))) short bf16x8;
typedef __attribute__((ext_vector_type(4))) float f32x4;
typedef unsigned int u32;
typedef unsigned short u16;
typedef unsigned long long u64;

#define SEQ 2048
#define DM 1024
#define NH 16
#define HD 64

// ---------- helpers ----------
__device__ __forceinline__ u16 f2bf(float f) {
  __hip_bfloat16 h = __float2bfloat16(f);   // pairs into v_cvt_pk_bf16_f32 (m240)
  return __builtin_bit_cast(u16, h);
}
__device__ __forceinline__ u32 pack2(float a, float b) {
  return (u32)f2bf(a) | ((u32)f2bf(b) << 16);
}
__device__ __forceinline__ float max3f(float a, float b, float c) {
  return fmaxf(fmaxf(a, b), c);   // fuses to v_max3_f32
}

typedef __attribute__((address_space(3))) u32 lds_u32;
typedef const __attribute__((address_space(1))) u32 gbl_u32;
__device__ __forceinline__ void gll16(const void* g, void* l) {
  // async global->LDS, 16B per lane; dest must be linear (wave base + lane*16)
  __builtin_amdgcn_global_load_lds((gbl_u32*)g, (lds_u32*)l, 16, 0, 0);
}

// ---------- fp32 -> bf16 cast of inputs+weights (segments contiguous in ws) ----------
__global__ __launch_bounds__(256) void cast_all(
    const float* __restrict__ q, const float* __restrict__ k, const float* __restrict__ v,
    const float* __restrict__ wq, const float* __restrict__ wk,
    const float* __restrict__ wv, const float* __restrict__ wf,
    u16* __restrict__ dst)
{
  int i4 = blockIdx.x * 256 + threadIdx.x;   // one float4 per thread, grid exact
  const float* s; int rel;
  if      (i4 < 2097152) { s = q;  rel = i4;           }
  else if (i4 < 4194304) { s = k;  rel = i4 - 2097152; }
  else if (i4 < 6291456) { s = v;  rel = i4 - 4194304; }
  else if (i4 < 6553600) { s = wq; rel = i4 - 6291456; }
  else if (i4 < 6815744) { s = wk; rel = i4 - 6553600; }
  else if (i4 < 7077888) { s = wv; rel = i4 - 6815744; }
  else                   { s = wf; rel = i4 - 7077888; }
  float4 val = ((const float4*)s)[rel];
  uint2 o; o.x = pack2(val.x, val.y); o.y = pack2(val.z, val.w);
  ((uint2*)dst)[i4] = o;
}

// ---------- int32 mask -> bitmask (1 bit per entry) ----------
__global__ __launch_bounds__(256) void maskbits(const int* __restrict__ mask, u32* __restrict__ bm) {
  int t = blockIdx.x * 256 + threadIdx.x;
  int v = mask[t];
  u64 bal = __ballot(v != 0);
  if ((threadIdx.x & 63) == 0) {
    bm[(t >> 5)]     = (u32)bal;
    bm[(t >> 5) + 1] = (u32)(bal >> 32);
  }
}

// ---------- GEMM: D[mi][ni] = sum_k Pm[mi][k]*Pn[ni][k]  (K=1024, bf16, fp32 acc) ----------
// MODE 0: Pm=W(1024r) Pn=X(8192r), out bf16 [B,H,S,64], bias[mi]     (Q,K proj)
// MODE 1: Pm=X(8192r) Pn=W(1024r), out bf16 [B,H,64,S] (V^T), bias[ni]
// MODE 2: Pm=W(1024r) Pn=AO(8192r), out fp32 [8192,1024], bias[mi]   (FC)
// scale: applied to (acc+bias) before store (Q-proj: 0.125*log2e; else 1.0)
template<int MODE>
__global__ __launch_bounds__(256) void gemm_bt(
    const u16* __restrict__ Pm, const u16* __restrict__ Pn,
    const float* __restrict__ bias, void* __restrict__ outp, float scale)
{
  __shared__ alignas(16) u16 Al[128 * 32];
  __shared__ alignas(16) u16 Bl[128 * 32];
  const int tid = threadIdx.x;
  const int l = tid & 63;
  const int wv = tid >> 6;
  const int lane15 = l & 15, g = l >> 4;
  const int wr = wv >> 1, wc = wv & 1;
  const int mBase = blockIdx.y * 128, nBase = blockIdx.x * 128;

  f32x4 acc[4][4];
#pragma unroll
  for (int a = 0; a < 4; ++a)
#pragma unroll
    for (int b = 0; b < 4; ++b) acc[a][b] = (f32x4){0.f, 0.f, 0.f, 0.f};

  const int srow = tid >> 2, skc = tid & 3;       // staging: row, 8-elem k-chunk
  const u16* gA = Pm + (size_t)(mBase + srow) * 1024 + skc * 8;
  const u16* gB = Pn + (size_t)(nBase + srow) * 1024 + skc * 8;

  for (int kt = 0; kt < 32; ++kt) {
    __syncthreads();
    const u16* a0 = gA + kt * 32;
    const u16* b0 = gB + kt * 32;
    gll16(a0,             &Al[tid * 8]);
    gll16(a0 + 64 * 1024, &Al[(tid + 256) * 8]);
    gll16(b0,             &Bl[tid * 8]);
    gll16(b0 + 64 * 1024, &Bl[(tid + 256) * 8]);
    __syncthreads();
    bf16x8 af[4], bff[4];
#pragma unroll
    for (int mt = 0; mt < 4; ++mt)
      af[mt] = *(const bf16x8*)&Al[(wr * 64 + mt * 16 + lane15) * 32 + g * 8];
#pragma unroll
    for (int nt = 0; nt < 4; ++nt)
      bff[nt] = *(const bf16x8*)&Bl[(wc * 64 + nt * 16 + lane15) * 32 + g * 8];
#pragma unroll
    for (int mt = 0; mt < 4; ++mt)
#pragma unroll
      for (int nt = 0; nt < 4; ++nt)
        acc[mt][nt] = __builtin_amdgcn_mfma_f32_16x16x32_bf16(af[mt], bff[nt], acc[mt][nt], 0, 0, 0);
  }

#pragma unroll
  for (int mt = 0; mt < 4; ++mt) {
    const int mi = mBase + wr * 64 + mt * 16 + g * 4;   // +reg (0..3) consecutive
#pragma unroll
    for (int nt = 0; nt < 4; ++nt) {
      const int ni = nBase + wc * 64 + nt * 16 + lane15;
      f32x4 v = acc[mt][nt];
      if constexpr (MODE == 0) {
        f32x4 bb = *(const f32x4*)&bias[mi];
        int b = ni >> 11, s = ni & 2047;
        int h = mi >> 6, dh = mi & 63;
        uint2 w;
        w.x = pack2((v[0] + bb[0]) * scale, (v[1] + bb[1]) * scale);
        w.y = pack2((v[2] + bb[2]) * scale, (v[3] + bb[3]) * scale);
        *(uint2*)&((u16*)outp)[((size_t)((b << 4) + h) * SEQ + s) * HD + dh] = w;
      } else if constexpr (MODE == 1) {
        float bv = bias[ni];
        int b = mi >> 11, s = mi & 2047;
        int h = ni >> 6, dh = ni & 63;
        uint2 w;
        w.x = pack2(v[0] + bv, v[1] + bv);
        w.y = pack2(v[2] + bv, v[3] + bv);
        *(uint2*)&((u16*)outp)[((size_t)((b << 4) + h) * HD + dh) * SEQ + s] = w;
      } else {
        f32x4 bb = *(const f32x4*)&bias[mi];
        f32x4 w = v + bb;
        *(f32x4*)&((float*)outp)[(size_t)ni * 1024 + mi] = w;
      }
    }
  }
}

// ---------- flash attention, 4 waves x 16 q-rows, KBLK=64 ----------
// K/V tiles LDS-staged (double-buffered, global_load_lds, XOR chunk swizzle lc^lr),
// counted vmcnt + raw s_barrier so prefetch stays in flight across barriers.
__global__ __launch_bounds__(256) void attn_kernel(
    const u16* __restrict__ Qb, const u16* __restrict__ Kb,
    const u16* __restrict__ Vt, const u32* __restrict__ bm,
    u16* __restrict__ AO)
{
  __shared__ alignas(16) u16 Kl[2][64 * 64];   // 16 KB (k-row major, 128B rows, chunk-swizzled)
  __shared__ alignas(16) u16 Vl[2][64 * 64];   // 16 KB (dh-row major, chunk-swizzled)
  __shared__ uint2 Pl[4][256];                 // 8 KB per-wave P^T transpose buffers
  const int bid = blockIdx.x;
  const int bh = (bid & 7) * 8 + ((bid >> 3) & 7);   // blocks of a head share bid%8 -> same XCD
  const int qt = bid >> 6;
  const int b = bh >> 4, h = bh & 15;
  const int tid = threadIdx.x;
  const int wv = tid >> 6, l = tid & 63;
  const int q16 = l & 15, g = l >> 4;
  const int lr = l >> 3, lc = l & 7;           // staging lane decomposition
  const int sx = q16 & 7;                      // read-side XOR (row&7)

  const u16* Qp = Qb + (size_t)bh * SEQ * HD;
  const u16* Kp = Kb + (size_t)bh * SEQ * HD;
  const u16* Vp = Vt + (size_t)bh * HD * SEQ;
  const int qrow = qt * 64 + wv * 16;

  const bf16x8 qf0 = *(const bf16x8*)&Qp[(qrow + q16) * HD + g * 8];
  const bf16x8 qf1 = *(const bf16x8*)&Qp[(qrow + q16) * HD + 32 + g * 8];
  const u32* bmq = bm + (size_t)(b * SEQ + qrow + q16) * (SEQ / 32);

  // per-lane staging source offsets (u16 units). Each wave issues instrs {2wv, 2wv+1} for K and V.
  // K instr i: LDS row = i*8+lr (local k), chunk lc holds source chunk lc^lr (involution).
  const int i0 = wv * 2;
  const u16* ksrc0 = Kp + (size_t)((i0 + 0) * 8 + lr) * HD + (lc ^ lr) * 8;
  const u16* ksrc1 = Kp + (size_t)((i0 + 1) * 8 + lr) * HD + (lc ^ lr) * 8;
  const u16* vsrc0 = Vp + (size_t)((i0 + 0) * 8 + lr) * SEQ + (lc ^ lr) * 8;
  const u16* vsrc1 = Vp + (size_t)((i0 + 1) * 8 + lr) * SEQ + (lc ^ lr) * 8;

  // all-ones bf16 A-fragment for the denominator MFMA
  union { u32 u[4]; bf16x8 v; } ones;
  ones.u[0] = ones.u[1] = ones.u[2] = ones.u[3] = 0x3F803F80u;

  float mrun = 8.0f;     // defer-max base (log2 domain); rescale branch keeps full generality
  f32x4 accO[4], accSum;
#pragma unroll
  for (int dt = 0; dt < 4; ++dt) accO[dt] = (f32x4){0.f, 0.f, 0.f, 0.f};
  accSum = (f32x4){0.f, 0.f, 0.f, 0.f};
  const f32x4 z = {0.f, 0.f, 0.f, 0.f};

  // prologue: stage tile 0 into buffer 0 (4 loads per wave)
  {
    gll16(ksrc0, &Kl[0][(i0 + 0) * 512 + l * 8]);
    gll16(ksrc1, &Kl[0][(i0 + 1) * 512 + l * 8]);
    gll16(vsrc0, &Vl[0][(i0 + 0) * 512 + l * 8]);
    gll16(vsrc1, &Vl[0][(i0 + 1) * 512 + l * 8]);
  }

  for (int kb = 0; kb < SEQ / 64; ++kb) {
    const int cur = kb & 1;
    const u32 w0 = bmq[kb * 2], w1 = bmq[kb * 2 + 1];
    if (kb < SEQ / 64 - 1) {
      const int nxt = cur ^ 1;
      const size_t ko = (size_t)(kb + 1) * 64;
      gll16(ksrc0 + ko * HD, &Kl[nxt][(i0 + 0) * 512 + l * 8]);
      gll16(ksrc1 + ko * HD, &Kl[nxt][(i0 + 1) * 512 + l * 8]);
      gll16(vsrc0 + ko,      &Vl[nxt][(i0 + 0) * 512 + l * 8]);
      gll16(vsrc1 + ko,      &Vl[nxt][(i0 + 1) * 512 + l * 8]);
      asm volatile("s_waitcnt vmcnt(4)" ::: "memory");   // cur staged (+mask); next stays in flight
    } else {
      asm volatile("s_waitcnt vmcnt(0)" ::: "memory");
    }
    __builtin_amdgcn_s_barrier();        // all waves' staging of cur visible
    __builtin_amdgcn_sched_barrier(0);

    const u16* Kc = &Kl[cur][0];
    const u16* Vc = &Vl[cur][0];

    f32x4 accS[4];
    __builtin_amdgcn_s_setprio(1);
#pragma unroll
    for (int n = 0; n < 4; ++n) {    // S^T tile: rows k, cols q
      const int rk = n * 16 + q16;
      bf16x8 kf0 = *(const bf16x8*)&Kc[rk * 64 + ((g ^ sx) * 8)];
      bf16x8 kf1 = *(const bf16x8*)&Kc[rk * 64 + (((4 + g) ^ sx) * 8)];
      accS[n] = __builtin_amdgcn_mfma_f32_16x16x32_bf16(kf0, qf0, z, 0, 0, 0);
      accS[n] = __builtin_amdgcn_mfma_f32_16x16x32_bf16(kf1, qf1, accS[n], 0, 0, 0);
    }
    __builtin_amdgcn_s_setprio(0);

    float s[16];
#pragma unroll
    for (int n = 0; n < 4; ++n) {
      const u32 nib = ((n & 2) ? w1 : w0) >> ((n & 1) * 16 + g * 4);  // 4 mask bits for this group
#pragma unroll
      for (int r = 0; r < 4; ++r)
        s[n * 4 + r] = ((nib >> r) & 1u) ? accS[n][r] : -1e9f;
    }
    float pmax;
    {
      float g0 = max3f(s[0],  s[1],  s[2]);
      float g1 = max3f(s[3],  s[4],  s[5]);
      float g2 = max3f(s[6],  s[7],  s[8]);
      float g3 = max3f(s[9],  s[10], s[11]);
      float g4 = max3f(s[12], s[13], s[14]);
      pmax = max3f(max3f(g0, g1, g2), max3f(g3, g4, s[15]), -INFINITY);
    }
    pmax = fmaxf(pmax, __shfl_xor(pmax, 16));
    pmax = fmaxf(pmax, __shfl_xor(pmax, 32));

    // T13 defer-max: rescale only if tile max exceeds running base by >12 (p<=2^12 bounded)
    if (!__all(pmax - mrun <= 12.0f)) {
      const float mnew = fmaxf(mrun, pmax);
      const float alpha = exp2f(mrun - mnew);
      accSum[0] *= alpha;
#pragma unroll
      for (int dt = 0; dt < 4; ++dt) {
        accO[dt][0] *= alpha; accO[dt][1] *= alpha;
        accO[dt][2] *= alpha; accO[dt][3] *= alpha;
      }
      mrun = mnew;
    }

    u16 pb[16];
#pragma unroll
    for (int i = 0; i < 16; ++i)
      pb[i] = f2bf(exp2f(s[i] - mrun));   // bare v_exp_f32 + paired cvt

    // write P^T (bf16) to per-wave LDS, 8B units XOR-swizzled by q (compiler manages lgkmcnt)
#pragma unroll
    for (int n = 0; n < 4; ++n) {
      uint2 pw;
      pw.x = (u32)pb[n * 4 + 0] | ((u32)pb[n * 4 + 1] << 16);
      pw.y = (u32)pb[n * 4 + 2] | ((u32)pb[n * 4 + 3] << 16);
      Pl[wv][q16 * 16 + ((n * 4 + g) ^ q16)] = pw;
    }
#pragma unroll
    for (int ch = 0; ch < 2; ++ch) {
      const int u0 = ch * 8 + g * 2;
      uint2 lo = Pl[wv][q16 * 16 + ((u0 + 0) ^ q16)];
      uint2 hi = Pl[wv][q16 * 16 + ((u0 + 1) ^ q16)];
      union { u32 u[4]; bf16x8 v; } pf;
      pf.u[0] = lo.x; pf.u[1] = lo.y; pf.u[2] = hi.x; pf.u[3] = hi.y;
      __builtin_amdgcn_s_setprio(1);
#pragma unroll
      for (int dt = 0; dt < 4; ++dt) {
        const int rv = dt * 16 + q16;
        bf16x8 vf = *(const bf16x8*)&Vc[rv * 64 + (((ch * 4 + g) ^ sx) * 8)];
        accO[dt] = __builtin_amdgcn_mfma_f32_16x16x32_bf16(vf, pf.v, accO[dt], 0, 0, 0);
      }
      // denominator: every reg of lane's col q16 accumulates its row-sum of P
      accSum = __builtin_amdgcn_mfma_f32_16x16x32_bf16(ones.v, pf.v, accSum, 0, 0, 0);
      __builtin_amdgcn_s_setprio(0);
    }
    __builtin_amdgcn_s_barrier();   // all waves done reading cur before it is re-staged
  }

  const float inv = 1.f / fmaxf(accSum[0], 1e-37f);
#pragma unroll
  for (int dt = 0; dt < 4; ++dt) {
    uint2 o;
    o.x = pack2(accO[dt][0] * inv, accO[dt][1] * inv);
    o.y = pack2(accO[dt][2] * inv, accO[dt][3] * inv);
    *(uint2*)&AO[(size_t)(b * SEQ + qrow + q16) * DM + h * HD + dt * 16 + g * 4] = o;
  }
}

// ---------- launch ----------
extern "C" void kernel_launch(void* const* d_in, const int* in_sizes, int n_in,
                              void* d_out, int out_size, void* d_ws, size_t ws_size,
                              hipStream_t stream) {
  const float* q  = (const float*)d_in[0];
  const float* k  = (const float*)d_in[1];
  const float* v  = (const float*)d_in[2];
  const int* mask = (const int*)d_in[3];
  const float* wq = (const float*)d_in[4];
  const float* bq = (const float*)d_in[5];
  const float* wk = (const float*)d_in[6];
  const float* bk = (const float*)d_in[7];
  const float* wv = (const float*)d_in[8];
  const float* bv = (const float*)d_in[9];
  const float* wf = (const float*)d_in[10];
  const float* bf = (const float*)d_in[11];

  // Workspace layout (u16 units). AO aliases XQ (XQ dead after Q-proj GEMM).
  u16* XQ = (u16*)d_ws;            // 8388608 u16 each for X tensors
  u16* XK = XQ + 8388608;
  u16* XV = XK + 8388608;
  u16* WQ = XV + 8388608;          // 1048576 u16 each for weights
  u16* WK = WQ + 1048576;
  u16* WV = WK + 1048576;
  u16* WF = WV + 1048576;
  u16* QB = WF + 1048576;          // projections, [B,H,S,64] (Q prescaled by 0.125*log2e)
  u16* KB = QB + 8388608;
  u16* VT = KB + 8388608;          // [B,H,64,S]
  u32* BM = (u32*)(VT + 8388608);  // bitmask [B][S][64] words (2 MB)
  u16* AO = XQ;                    // attn out merged [8192,1024] — reuses XQ

  const float qscale = 0.125f * 1.44269504088896f;   // 1/sqrt(Dh) * log2(e)

  cast_all<<<28672, 256, 0, stream>>>(q, k, v, wq, wk, wv, wf, XQ);
  maskbits<<<65536, 256, 0, stream>>>(mask, BM);
  gemm_bt<0><<<dim3(64, 8), 256, 0, stream>>>(WQ, XQ, bq, QB, qscale);
  gemm_bt<0><<<dim3(64, 8), 256, 0, stream>>>(WK, XK, bk, KB, 1.0f);
  gemm_bt<1><<<dim3(8, 64), 256, 0, stream>>>(XV, WV, bv, VT, 1.0f);
  attn_kernel<<<2048, 256, 0, stream>>>(QB, KB, VT, BM, AO);
  gemm_bt<2><<<dim3(64, 8), 256, 0, stream>>>(WF, AO, bf, (float*)d_out, 1.0f);
}

// Round 8
// 472.570 us; speedup vs baseline: 1.7163x; 1.0319x over previous
//
#include <hip/hip_runtime.h>
#include <hip/hip_bf16.h>

// MHA: y = softmax(mask(QK^T/8)) V, with bf16 MFMA pipeline.
// B=4, S=2048, D=1024, H=16, Dh=64.
// Q-projection prescaled by 0.125*log2(e): softmax computed in base-2 domain.
// Softmax denominator via MFMA (ones-row x P^T). R5: K/V LDS staging + counted vmcnt.
// R6/R7: v_cvt_pk_bf16_f32 asm packing, in-place mask/exp on accS, 128-VGPR budget,
//     fused QKV projection launch. (R7 = R6 resubmit after infra timeout.)

typedef __attribute__((ext_vector_type(8))) short bf16x8;
typedef __attribute__((ext_vector_type(4))) float f32x4;
typedef unsigned int u32;
typedef unsigned short u16;
typedef unsigned long long u64;

#define SEQ 2048
#define DM 1024
#define NH 16
#define HD 64

// ---------- helpers ----------
__device__ __forceinline__ u32 pack2(float a, float b) {
  u32 d;
  asm("v_cvt_pk_bf16_f32 %0, %1, %2" : "=v"(d) : "v"(a), "v"(b));  // lo=a, hi=b, RNE
  return d;
}
__device__ __forceinline__ float max3f(float a, float b, float c) {
  return fmaxf(fmaxf(a, b), c);   // fuses to v_max3_f32
}

typedef __attribute__((address_space(3))) u32 lds_u32;
typedef const __attribute__((address_space(1))) u32 gbl_u32;
__device__ __forceinline__ void gll16(const void* g, void* l) {
  // async global->LDS, 16B per lane; dest must be linear (wave base + lane*16)
  __builtin_amdgcn_global_load_lds((gbl_u32*)g, (lds_u32*)l, 16, 0, 0);
}

// ---------- fp32 -> bf16 cast of inputs+weights (segments contiguous in ws) ----------
__global__ __launch_bounds__(256) void cast_all(
    const float* __restrict__ q, const float* __restrict__ k, const float* __restrict__ v,
    const float* __restrict__ wq, const float* __restrict__ wk,
    const float* __restrict__ wv, const float* __restrict__ wf,
    u16* __restrict__ dst)
{
  int i4 = blockIdx.x * 256 + threadIdx.x;   // one float4 per thread, grid exact
  const float* s; int rel;
  if      (i4 < 2097152) { s = q;  rel = i4;           }
  else if (i4 < 4194304) { s = k;  rel = i4 - 2097152; }
  else if (i4 < 6291456) { s = v;  rel = i4 - 4194304; }
  else if (i4 < 6553600) { s = wq; rel = i4 - 6291456; }
  else if (i4 < 6815744) { s = wk; rel = i4 - 6553600; }
  else if (i4 < 7077888) { s = wv; rel = i4 - 6815744; }
  else                   { s = wf; rel = i4 - 7077888; }
  float4 val = ((const float4*)s)[rel];
  uint2 o; o.x = pack2(val.x, val.y); o.y = pack2(val.z, val.w);
  ((uint2*)dst)[i4] = o;
}

// ---------- int32 mask -> bitmask (1 bit per entry) ----------
__global__ __launch_bounds__(256) void maskbits(const int* __restrict__ mask, u32* __restrict__ bm) {
  int t = blockIdx.x * 256 + threadIdx.x;
  int v = mask[t];
  u64 bal = __ballot(v != 0);
  if ((threadIdx.x & 63) == 0) {
    bm[(t >> 5)]     = (u32)bal;
    bm[(t >> 5) + 1] = (u32)(bal >> 32);
  }
}

// ---------- GEMM core macro-shape: D[mi][ni] = sum_k Pm[mi][k]*Pn[ni][k], K=1024 ----------
// Fused QKV projections: z=0 Q-proj, z=1 K-proj (out [B,H,S,64]); z=2 V-proj (out [B,H,64,S]).
__global__ __launch_bounds__(256) void gemm_qkv(
    const u16* __restrict__ WQp, const u16* __restrict__ XQp, const float* __restrict__ bq,
    const u16* __restrict__ WKp, const u16* __restrict__ XKp, const float* __restrict__ bk,
    const u16* __restrict__ WVp, const u16* __restrict__ XVp, const float* __restrict__ bv,
    u16* __restrict__ QB, u16* __restrict__ KB, u16* __restrict__ VT, float qscale)
{
  __shared__ alignas(16) u16 Al[128 * 32];
  __shared__ alignas(16) u16 Bl[128 * 32];
  const int z = blockIdx.z;
  const u16 *Pm, *Pn; const float* bias;
  int mBase, nBase;
  if (z == 0)      { Pm = WQp; Pn = XQp; bias = bq; mBase = blockIdx.y * 128; nBase = blockIdx.x * 128; }
  else if (z == 1) { Pm = WKp; Pn = XKp; bias = bk; mBase = blockIdx.y * 128; nBase = blockIdx.x * 128; }
  else             { Pm = XVp; Pn = WVp; bias = bv; mBase = blockIdx.x * 128; nBase = blockIdx.y * 128; }

  const int tid = threadIdx.x;
  const int l = tid & 63;
  const int wv = tid >> 6;
  const int lane15 = l & 15, g = l >> 4;
  const int wr = wv >> 1, wc = wv & 1;

  f32x4 acc[4][4];
#pragma unroll
  for (int a = 0; a < 4; ++a)
#pragma unroll
    for (int b = 0; b < 4; ++b) acc[a][b] = (f32x4){0.f, 0.f, 0.f, 0.f};

  const int srow = tid >> 2, skc = tid & 3;       // staging: row, 8-elem k-chunk
  const u16* gA = Pm + (size_t)(mBase + srow) * 1024 + skc * 8;
  const u16* gB = Pn + (size_t)(nBase + srow) * 1024 + skc * 8;

  for (int kt = 0; kt < 32; ++kt) {
    __syncthreads();
    const u16* a0 = gA + kt * 32;
    const u16* b0 = gB + kt * 32;
    gll16(a0,             &Al[tid * 8]);
    gll16(a0 + 64 * 1024, &Al[(tid + 256) * 8]);
    gll16(b0,             &Bl[tid * 8]);
    gll16(b0 + 64 * 1024, &Bl[(tid + 256) * 8]);
    __syncthreads();
    bf16x8 af[4], bff[4];
#pragma unroll
    for (int mt = 0; mt < 4; ++mt)
      af[mt] = *(const bf16x8*)&Al[(wr * 64 + mt * 16 + lane15) * 32 + g * 8];
#pragma unroll
    for (int nt = 0; nt < 4; ++nt)
      bff[nt] = *(const bf16x8*)&Bl[(wc * 64 + nt * 16 + lane15) * 32 + g * 8];
#pragma unroll
    for (int mt = 0; mt < 4; ++mt)
#pragma unroll
      for (int nt = 0; nt < 4; ++nt)
        acc[mt][nt] = __builtin_amdgcn_mfma_f32_16x16x32_bf16(af[mt], bff[nt], acc[mt][nt], 0, 0, 0);
  }

  if (z <= 1) {
    const float scale = (z == 0) ? qscale : 1.0f;
    u16* outp = (z == 0) ? QB : KB;
#pragma unroll
    for (int mt = 0; mt < 4; ++mt) {
      const int mi = mBase + wr * 64 + mt * 16 + g * 4;
      f32x4 bb = *(const f32x4*)&bias[mi];
#pragma unroll
      for (int nt = 0; nt < 4; ++nt) {
        const int ni = nBase + wc * 64 + nt * 16 + lane15;
        f32x4 v = acc[mt][nt];
        int b = ni >> 11, s = ni & 2047;
        int h = mi >> 6, dh = mi & 63;
        uint2 w;
        w.x = pack2((v[0] + bb[0]) * scale, (v[1] + bb[1]) * scale);
        w.y = pack2((v[2] + bb[2]) * scale, (v[3] + bb[3]) * scale);
        *(uint2*)&outp[((size_t)((b << 4) + h) * SEQ + s) * HD + dh] = w;
      }
    }
  } else {
#pragma unroll
    for (int mt = 0; mt < 4; ++mt) {
      const int mi = mBase + wr * 64 + mt * 16 + g * 4;   // X-row = (b,s)
#pragma unroll
      for (int nt = 0; nt < 4; ++nt) {
        const int ni = nBase + wc * 64 + nt * 16 + lane15; // V channel = (h,dh)
        float bvv = bias[ni];
        f32x4 v = acc[mt][nt];
        int b = mi >> 11, s = mi & 2047;
        int h = ni >> 6, dh = ni & 63;
        uint2 w;
        w.x = pack2(v[0] + bvv, v[1] + bvv);
        w.y = pack2(v[2] + bvv, v[3] + bvv);
        *(uint2*)&VT[((size_t)((b << 4) + h) * HD + dh) * SEQ + s] = w;
      }
    }
  }
}

// ---------- FC GEMM: out fp32 [8192,1024] ----------
__global__ __launch_bounds__(256) void gemm_fc(
    const u16* __restrict__ Pm, const u16* __restrict__ Pn,
    const float* __restrict__ bias, float* __restrict__ outp)
{
  __shared__ alignas(16) u16 Al[128 * 32];
  __shared__ alignas(16) u16 Bl[128 * 32];
  const int tid = threadIdx.x;
  const int l = tid & 63;
  const int wv = tid >> 6;
  const int lane15 = l & 15, g = l >> 4;
  const int wr = wv >> 1, wc = wv & 1;
  const int mBase = blockIdx.y * 128, nBase = blockIdx.x * 128;

  f32x4 acc[4][4];
#pragma unroll
  for (int a = 0; a < 4; ++a)
#pragma unroll
    for (int b = 0; b < 4; ++b) acc[a][b] = (f32x4){0.f, 0.f, 0.f, 0.f};

  const int srow = tid >> 2, skc = tid & 3;
  const u16* gA = Pm + (size_t)(mBase + srow) * 1024 + skc * 8;
  const u16* gB = Pn + (size_t)(nBase + srow) * 1024 + skc * 8;

  for (int kt = 0; kt < 32; ++kt) {
    __syncthreads();
    const u16* a0 = gA + kt * 32;
    const u16* b0 = gB + kt * 32;
    gll16(a0,             &Al[tid * 8]);
    gll16(a0 + 64 * 1024, &Al[(tid + 256) * 8]);
    gll16(b0,             &Bl[tid * 8]);
    gll16(b0 + 64 * 1024, &Bl[(tid + 256) * 8]);
    __syncthreads();
    bf16x8 af[4], bff[4];
#pragma unroll
    for (int mt = 0; mt < 4; ++mt)
      af[mt] = *(const bf16x8*)&Al[(wr * 64 + mt * 16 + lane15) * 32 + g * 8];
#pragma unroll
    for (int nt = 0; nt < 4; ++nt)
      bff[nt] = *(const bf16x8*)&Bl[(wc * 64 + nt * 16 + lane15) * 32 + g * 8];
#pragma unroll
    for (int mt = 0; mt < 4; ++mt)
#pragma unroll
      for (int nt = 0; nt < 4; ++nt)
        acc[mt][nt] = __builtin_amdgcn_mfma_f32_16x16x32_bf16(af[mt], bff[nt], acc[mt][nt], 0, 0, 0);
  }

#pragma unroll
  for (int mt = 0; mt < 4; ++mt) {
    const int mi = mBase + wr * 64 + mt * 16 + g * 4;
    f32x4 bb = *(const f32x4*)&bias[mi];
#pragma unroll
    for (int nt = 0; nt < 4; ++nt) {
      const int ni = nBase + wc * 64 + nt * 16 + lane15;
      f32x4 w = acc[mt][nt] + bb;
      *(f32x4*)&outp[(size_t)ni * 1024 + mi] = w;
    }
  }
}

// ---------- flash attention, 4 waves x 16 q-rows, KBLK=64 ----------
// K/V tiles LDS-staged (double-buffered, global_load_lds, XOR chunk swizzle lc^lr),
// counted vmcnt + raw s_barrier so prefetch stays in flight across barriers.
__global__ __launch_bounds__(256, 4) void attn_kernel(
    const u16* __restrict__ Qb, const u16* __restrict__ Kb,
    const u16* __restrict__ Vt, const u32* __restrict__ bm,
    u16* __restrict__ AO)
{
  __shared__ alignas(16) u16 Kl[2][64 * 64];   // 16 KB (k-row major, 128B rows, chunk-swizzled)
  __shared__ alignas(16) u16 Vl[2][64 * 64];   // 16 KB (dh-row major, chunk-swizzled)
  __shared__ uint2 Pl[4][256];                 // 8 KB per-wave P^T transpose buffers
  const int bid = blockIdx.x;
  const int bh = (bid & 7) * 8 + ((bid >> 3) & 7);   // blocks of a head share bid%8 -> same XCD
  const int qt = bid >> 6;
  const int b = bh >> 4, h = bh & 15;
  const int tid = threadIdx.x;
  const int wv = tid >> 6, l = tid & 63;
  const int q16 = l & 15, g = l >> 4;
  const int lr = l >> 3, lc = l & 7;           // staging lane decomposition
  const int sx = q16 & 7;                      // read-side XOR (row&7)

  const u16* Qp = Qb + (size_t)bh * SEQ * HD;
  const u16* Kp = Kb + (size_t)bh * SEQ * HD;
  const u16* Vp = Vt + (size_t)bh * HD * SEQ;
  const int qrow = qt * 64 + wv * 16;

  const bf16x8 qf0 = *(const bf16x8*)&Qp[(qrow + q16) * HD + g * 8];
  const bf16x8 qf1 = *(const bf16x8*)&Qp[(qrow + q16) * HD + 32 + g * 8];
  const u32* bmq = bm + (size_t)(b * SEQ + qrow + q16) * (SEQ / 32);

  // staging sources (u16 units); advanced by pointer bump each tile
  const int i0 = wv * 2;
  const u16* ks0 = Kp + (size_t)((i0 + 0) * 8 + lr) * HD + (lc ^ lr) * 8;
  const u16* ks1 = Kp + (size_t)((i0 + 1) * 8 + lr) * HD + (lc ^ lr) * 8;
  const u16* vs0 = Vp + (size_t)((i0 + 0) * 8 + lr) * SEQ + (lc ^ lr) * 8;
  const u16* vs1 = Vp + (size_t)((i0 + 1) * 8 + lr) * SEQ + (lc ^ lr) * 8;

  // all-ones bf16 A-fragment for the denominator MFMA
  union { u32 u[4]; bf16x8 v; } ones;
  ones.u[0] = ones.u[1] = ones.u[2] = ones.u[3] = 0x3F803F80u;

  float mrun = 8.0f;     // defer-max base (log2 domain); rescale branch keeps full generality
  f32x4 accO[4], accSum;
#pragma unroll
  for (int dt = 0; dt < 4; ++dt) accO[dt] = (f32x4){0.f, 0.f, 0.f, 0.f};
  accSum = (f32x4){0.f, 0.f, 0.f, 0.f};
  const f32x4 z = {0.f, 0.f, 0.f, 0.f};

  // prologue: stage tile 0 into buffer 0 (4 loads per wave)
  gll16(ks0, &Kl[0][(i0 + 0) * 512 + l * 8]);
  gll16(ks1, &Kl[0][(i0 + 1) * 512 + l * 8]);
  gll16(vs0, &Vl[0][(i0 + 0) * 512 + l * 8]);
  gll16(vs1, &Vl[0][(i0 + 1) * 512 + l * 8]);
  ks0 += 64 * HD; ks1 += 64 * HD; vs0 += 64; vs1 += 64;

  for (int kb = 0; kb < SEQ / 64; ++kb) {
    const int cur = kb & 1;
    const u32 w0 = bmq[kb * 2], w1 = bmq[kb * 2 + 1];
    if (kb < SEQ / 64 - 1) {
      const int nxt = cur ^ 1;
      gll16(ks0, &Kl[nxt][(i0 + 0) * 512 + l * 8]);
      gll16(ks1, &Kl[nxt][(i0 + 1) * 512 + l * 8]);
      gll16(vs0, &Vl[nxt][(i0 + 0) * 512 + l * 8]);
      gll16(vs1, &Vl[nxt][(i0 + 1) * 512 + l * 8]);
      ks0 += 64 * HD; ks1 += 64 * HD; vs0 += 64; vs1 += 64;
      asm volatile("s_waitcnt vmcnt(4)" ::: "memory");   // cur staged; next stays in flight
    } else {
      asm volatile("s_waitcnt vmcnt(0)" ::: "memory");
    }
    __builtin_amdgcn_s_barrier();        // all waves' staging of cur visible
    __builtin_amdgcn_sched_barrier(0);

    const u16* Kc = &Kl[cur][0];
    const u16* Vc = &Vl[cur][0];

    f32x4 accS[4];
#pragma unroll
    for (int n = 0; n < 4; ++n) {    // S^T tile: rows k, cols q
      const int rk = n * 16 + q16;
      bf16x8 kf0 = *(const bf16x8*)&Kc[rk * 64 + ((g ^ sx) * 8)];
      bf16x8 kf1 = *(const bf16x8*)&Kc[rk * 64 + (((4 + g) ^ sx) * 8)];
      accS[n] = __builtin_amdgcn_mfma_f32_16x16x32_bf16(kf0, qf0, z, 0, 0, 0);
      accS[n] = __builtin_amdgcn_mfma_f32_16x16x32_bf16(kf1, qf1, accS[n], 0, 0, 0);
    }

    // mask in place on accS (4 mask bits per (n,g) nibble)
#pragma unroll
    for (int n = 0; n < 4; ++n) {
      const u32 nib = ((n & 2) ? w1 : w0) >> ((n & 1) * 16 + g * 4);
#pragma unroll
      for (int r = 0; r < 4; ++r)
        accS[n][r] = ((nib >> r) & 1u) ? accS[n][r] : -1e9f;
    }

    // max over 16 via v_max3 tree, then across the 4 k-groups
    float t0 = max3f(accS[0][0], accS[0][1], accS[0][2]);
    float t1 = max3f(accS[0][3], accS[1][0], accS[1][1]);
    float t2 = max3f(accS[1][2], accS[1][3], accS[2][0]);
    float t3 = max3f(accS[2][1], accS[2][2], accS[2][3]);
    float t4 = max3f(accS[3][0], accS[3][1], accS[3][2]);
    float pmax = fmaxf(max3f(t0, t1, t2), max3f(t3, t4, accS[3][3]));
    pmax = fmaxf(pmax, __shfl_xor(pmax, 16));
    pmax = fmaxf(pmax, __shfl_xor(pmax, 32));

    // T13 defer-max: rescale only if tile max exceeds running base by >12 (p<=2^12 bounded)
    if (!__all(pmax - mrun <= 12.0f)) {
      const float mnew = fmaxf(mrun, pmax);
      const float alpha = exp2f(mrun - mnew);
      accSum[0] *= alpha;
#pragma unroll
      for (int dt = 0; dt < 4; ++dt) {
        accO[dt][0] *= alpha; accO[dt][1] *= alpha;
        accO[dt][2] *= alpha; accO[dt][3] *= alpha;
      }
      mrun = mnew;
    }

    // P = exp2(S - mrun), packed straight to bf16 pairs; write P^T to per-wave LDS
#pragma unroll
    for (int n = 0; n < 4; ++n) {
      float p0 = exp2f(accS[n][0] - mrun);
      float p1 = exp2f(accS[n][1] - mrun);
      float p2 = exp2f(accS[n][2] - mrun);
      float p3 = exp2f(accS[n][3] - mrun);
      uint2 pw; pw.x = pack2(p0, p1); pw.y = pack2(p2, p3);
      Pl[wv][q16 * 16 + ((n * 4 + g) ^ q16)] = pw;
    }
#pragma unroll
    for (int ch = 0; ch < 2; ++ch) {
      const int u0 = ch * 8 + g * 2;
      uint2 lo = Pl[wv][q16 * 16 + ((u0 + 0) ^ q16)];
      uint2 hi = Pl[wv][q16 * 16 + ((u0 + 1) ^ q16)];
      union { u32 u[4]; bf16x8 v; } pf;
      pf.u[0] = lo.x; pf.u[1] = lo.y; pf.u[2] = hi.x; pf.u[3] = hi.y;
#pragma unroll
      for (int dt = 0; dt < 4; ++dt) {
        const int rv = dt * 16 + q16;
        bf16x8 vf = *(const bf16x8*)&Vc[rv * 64 + (((ch * 4 + g) ^ sx) * 8)];
        accO[dt] = __builtin_amdgcn_mfma_f32_16x16x32_bf16(vf, pf.v, accO[dt], 0, 0, 0);
      }
      // denominator: every reg of lane's col q16 accumulates its row-sum of P
      accSum = __builtin_amdgcn_mfma_f32_16x16x32_bf16(ones.v, pf.v, accSum, 0, 0, 0);
    }
    __builtin_amdgcn_s_barrier();   // all waves done reading cur before it is re-staged
  }

  const float inv = 1.f / fmaxf(accSum[0], 1e-37f);
#pragma unroll
  for (int dt = 0; dt < 4; ++dt) {
    uint2 o;
    o.x = pack2(accO[dt][0] * inv, accO[dt][1] * inv);
    o.y = pack2(accO[dt][2] * inv, accO[dt][3] * inv);
    *(uint2*)&AO[(size_t)(b * SEQ + qrow + q16) * DM + h * HD + dt * 16 + g * 4] = o;
  }
}

// ---------- launch ----------
extern "C" void kernel_launch(void* const* d_in, const int* in_sizes, int n_in,
                              void* d_out, int out_size, void* d_ws, size_t ws_size,
                              hipStream_t stream) {
  const float* q  = (const float*)d_in[0];
  const float* k  = (const float*)d_in[1];
  const float* v  = (const float*)d_in[2];
  const int* mask = (const int*)d_in[3];
  const float* wq = (const float*)d_in[4];
  const float* bq = (const float*)d_in[5];
  const float* wk = (const float*)d_in[6];
  const float* bk = (const float*)d_in[7];
  const float* wv = (const float*)d_in[8];
  const float* bv = (const float*)d_in[9];
  const float* wf = (const float*)d_in[10];
  const float* bf = (const float*)d_in[11];

  // Workspace layout (u16 units). AO aliases XQ (XQ dead after Q-proj GEMM).
  u16* XQ = (u16*)d_ws;            // 8388608 u16 each for X tensors
  u16* XK = XQ + 8388608;
  u16* XV = XK + 8388608;
  u16* WQ = XV + 8388608;          // 1048576 u16 each for weights
  u16* WK = WQ + 1048576;
  u16* WV = WK + 1048576;
  u16* WF = WV + 1048576;
  u16* QB = WF + 1048576;          // projections, [B,H,S,64] (Q prescaled by 0.125*log2e)
  u16* KB = QB + 8388608;
  u16* VT = KB + 8388608;          // [B,H,64,S]
  u32* BM = (u32*)(VT + 8388608);  // bitmask [B][S][64] words (2 MB)
  u16* AO = XQ;                    // attn out merged [8192,1024] — reuses XQ

  const float qscale = 0.125f * 1.44269504088896f;   // 1/sqrt(Dh) * log2(e)

  cast_all<<<28672, 256, 0, stream>>>(q, k, v, wq, wk, wv, wf, XQ);
  maskbits<<<65536, 256, 0, stream>>>(mask, BM);
  gemm_qkv<<<dim3(64, 8, 3), 256, 0, stream>>>(WQ, XQ, bq, WK, XK, bk, WV, XV, bv,
                                               QB, KB, VT, qscale);
  attn_kernel<<<2048, 256, 0, stream>>>(QB, KB, VT, BM, AO);
  gemm_fc<<<dim3(64, 8), 256, 0, stream>>>(WF, AO, bf, (float*)d_out);
}